// Round 4
// baseline (141.102 us; speedup 1.0000x reference)
//
#include <hip/hip_runtime.h>
#include <stdint.h>

#define NXS 8192
#define HS  1024

typedef __attribute__((ext_vector_type(8))) short short8;
typedef __attribute__((ext_vector_type(4))) float f32x4;

__device__ __forceinline__ float bf2f(uint32_t b) {
    union { uint32_t u; float f; } c; c.u = b << 16; return c.f;
}
__device__ __forceinline__ uint16_t f2bf(float f) {
    union { float f; uint32_t u; } c; c.f = f;
    return (uint16_t)((c.u + 0x7fffu + ((c.u >> 16) & 1u)) >> 16);
}
__device__ __forceinline__ void async_cp16(const void* g, void* l) {
    __builtin_amdgcn_global_load_lds(
        (const __attribute__((address_space(1))) void*)g,
        (__attribute__((address_space(3))) void*)l,
        16, 0, 0);
}
// Counted-vmcnt barrier (m201 idiom): retire the 4 oldest vmem ops (A-stage),
// leave the 8 B-stream loads in flight across the barrier. Memory clobber pins
// all surrounding memory ops; ds_reads of the staged buffer sit AFTER this, so
// ordering is stage-retire -> barrier -> ds_read.
__device__ __forceinline__ void wait8_barrier() {
    asm volatile("s_waitcnt vmcnt(8)" ::: "memory");
    __builtin_amdgcn_s_barrier();
}

// ---- K01: merged prep (unchanged) ----
__global__ __launch_bounds__(256) void k01(
    const float* __restrict__ x, const float* __restrict__ W1,
    const float* __restrict__ b1, const float* __restrict__ W2,
    const float* __restrict__ b3, uint16_t* __restrict__ Z1,
    uint16_t* __restrict__ Bp1, uint16_t* __restrict__ Bp2,
    uint16_t* __restrict__ W1T, float* __restrict__ out)
{
    __shared__ float xs[8][8];
    const int b = blockIdx.x, t = threadIdx.x;
    if (b < 1024) {
        const int n0 = b * 8;
        if (t < 64) xs[t >> 3][t & 7] = x[n0 * 8 + t];
        const int j = t * 4;
        float w[4][8];
#pragma unroll
        for (int c = 0; c < 4; ++c) {
            float4 w0 = *(const float4*)(W1 + (j + c) * 8);
            float4 w1 = *(const float4*)(W1 + (j + c) * 8 + 4);
            w[c][0] = w0.x; w[c][1] = w0.y; w[c][2] = w0.z; w[c][3] = w0.w;
            w[c][4] = w1.x; w[c][5] = w1.y; w[c][6] = w1.z; w[c][7] = w1.w;
        }
        float4 bb = *(const float4*)(b1 + j);
        const float bv[4] = {bb.x, bb.y, bb.z, bb.w};
        __syncthreads();
#pragma unroll
        for (int s = 0; s < 8; ++s) {
            ushort4 o;
            uint16_t* op = (uint16_t*)&o;
#pragma unroll
            for (int c = 0; c < 4; ++c) {
                float sum = bv[c];
#pragma unroll
                for (int k = 0; k < 8; ++k) sum += xs[s][k] * w[c][k];
                op[c] = f2bf(tanhf(sum));
            }
            *(ushort4*)(Z1 + (size_t)(n0 + s) * HS + j) = o;
        }
    } else if (b < 1536) {
        const int tid = (b - 1024) * 256 + t;            // 0..131071
        const int l = tid & 63, c = (tid >> 6) & 31, g = tid >> 11;
        const int lr = l & 15, lq = l >> 4;
        const float* src = W2 + (size_t)(g * 16 + lr) * HS + c * 32 + lq * 8;
        float4 a0 = *(const float4*)src;
        float4 a1 = *(const float4*)(src + 4);
        uint16_t o[8];
        o[0] = f2bf(a0.x); o[1] = f2bf(a0.y); o[2] = f2bf(a0.z); o[3] = f2bf(a0.w);
        o[4] = f2bf(a1.x); o[5] = f2bf(a1.y); o[6] = f2bf(a1.z); o[7] = f2bf(a1.w);
        *(ushort4*)(Bp1 + (size_t)tid * 8)     = *(ushort4*)&o[0];
        *(ushort4*)(Bp1 + (size_t)tid * 8 + 4) = *(ushort4*)&o[4];
    } else if (b < 2048) {
        const int tid = (b - 1536) * 256 + t;
        const int l = tid & 63, c = (tid >> 6) & 31, g = tid >> 11;
        const int lr = l & 15, lq = l >> 4;
        uint16_t o[8];
#pragma unroll
        for (int j2 = 0; j2 < 8; ++j2)
            o[j2] = f2bf(W2[(size_t)(c * 32 + lq * 8 + j2) * HS + g * 16 + lr]);
        *(ushort4*)(Bp2 + (size_t)tid * 8)     = *(ushort4*)&o[0];
        *(ushort4*)(Bp2 + (size_t)tid * 8 + 4) = *(ushort4*)&o[4];
    } else if (b < 2336) {
        const int idx = (b - 2048) * 256 + t;            // 0..73727
        out[idx] = (idx < NXS) ? b3[0] : 0.f;
    } else {
        const int idx = (b - 2336) * 256 + t;            // 0..16383
        const int r = idx >> 10, cc = idx & 1023;
        W1T[idx] = (r < 8) ? f2bf(W1[cc * 8 + r]) : (uint16_t)0;
    }
}

// -------- GEMM: 128x128 tile, 4 waves (2x2), BK=64, A via LDS dbuf (xor-8
// swizzle, conflict-free ds_read_b128), B direct-VGPR stream.
// Counted-vmcnt schedule, 2x-unrolled K-loop (8 double-steps) so the B-frag
// ping-pong (bX/bY) is register renaming and the buffer index is static.
// Per phase: issue 4 gload_lds (oldest) -> issue 8 B-loads -> MFMA on the
// other buffer -> vmcnt(8) retires only the stage ops -> s_barrier. The 8
// B-loads stay in flight across the barrier (compiler's pre-MFMA wait
// catches them next phase).
// MODE 0: C = Z1 @ W2^T (Bp1); epilogue: tanh -> V (bf16), y atomics
// MODE 1: C = U = V @ W2 (Bp2); fused MFMA dydx epilogue via W1T
template <int MODE>
__global__ __launch_bounds__(256, 2) void gemm_k(
    const uint16_t* __restrict__ A, const uint16_t* __restrict__ Bp,
    const float* __restrict__ bias, const float* __restrict__ W3,
    uint16_t* __restrict__ Out, float* __restrict__ yOut,
    const uint16_t* __restrict__ Z1, const uint16_t* __restrict__ W1T,
    float* __restrict__ dOut)
{
    // A dbuf: 2 x 16384 B at [0,32768). MODE1 epilogue c-matrix: 128x136 u16.
    constexpr int SMEM_U16 = (MODE == 1) ? 17408 : 16384;
    __shared__ __attribute__((aligned(16))) uint16_t smem[SMEM_U16];
    const int t = threadIdx.x;
    const int wave = t >> 6, lane = t & 63;
    const int lq = lane >> 4, lr = lane & 15;
    const int wr = wave >> 1, wc = wave & 1;
    const int rowBase = blockIdx.x * 128;
    const int colBase = blockIdx.y * 128;

    // A staging: 1024 segs of 16B per buffer (128 rows x 8 slots), 4/thread.
    // LDS dest linear; global source slot pre-swizzled qA = (s&7)^(rA&7).
    const uint16_t* gA[4];
#pragma unroll
    for (int i = 0; i < 4; ++i) {
        int s = t + i * 256;
        int rA = s >> 3, qA = (s & 7) ^ (rA & 7);
        gA[i] = A + (size_t)(rowBase + rA) * HS + qA * 8;
    }

    // B fragment streams: wave wc owns groups colBase/16 + wc*4 + tj.
    const uint16_t* pB[4];
#pragma unroll
    for (int tj = 0; tj < 4; ++tj)
        pB[tj] = Bp + ((size_t)(colBase >> 4) + wc * 4 + tj) * 16384
                    + (size_t)lane * 8;

    f32x4 acc[4][4] = {};
    short8 bX[4][2], bY[4][2];

#define STAGE_TO(bufByte, step)                                              \
    {                                                                        \
        _Pragma("unroll")                                                    \
        for (int k_ = 0; k_ < 4; ++k_)                                       \
            async_cp16(gA[k_] + (step) * 64,                                 \
                       (char*)smem + (bufByte) + t * 16 + k_ * 4096);        \
        asm volatile("" ::: "memory");                                       \
    }
#define LOADB(dst, step)                                                     \
    {                                                                        \
        _Pragma("unroll")                                                    \
        for (int tj_ = 0; tj_ < 4; ++tj_) {                                  \
            dst[tj_][0] = *(const short8*)(pB[tj_] + (step) * 1024);         \
            dst[tj_][1] = *(const short8*)(pB[tj_] + (step) * 1024 + 512);   \
        }                                                                    \
    }
#define COMPUTE(pAbase, breg)                                                \
    {                                                                        \
        const uint16_t* pA_ = (pAbase);                                      \
        _Pragma("unroll")                                                    \
        for (int kk_ = 0; kk_ < 2; ++kk_) {                                  \
            short8 af_[4];                                                   \
            _Pragma("unroll")                                                \
            for (int ti_ = 0; ti_ < 4; ++ti_) {                              \
                int ar_ = wr * 64 + ti_ * 16 + lr;                           \
                af_[ti_] = *(const short8*)(pA_ + ar_ * 64                   \
                            + ((((kk_ << 2) + lq) ^ (ar_ & 7)) << 3));       \
            }                                                                \
            _Pragma("unroll")                                                \
            for (int ti_ = 0; ti_ < 4; ++ti_)                                \
                _Pragma("unroll")                                            \
                for (int tj_ = 0; tj_ < 4; ++tj_)                            \
                    acc[ti_][tj_] = __builtin_amdgcn_mfma_f32_16x16x32_bf16( \
                        af_[ti_], breg[tj_][kk_], acc[ti_][tj_], 0, 0, 0);   \
        }                                                                    \
    }

    // prologue: stage step 0 into buf0 (oldest vmem), load bX = B_0
    STAGE_TO(0, 0)
    LOADB(bX, 0)
    wait8_barrier();   // retire the 4 stage ops; bX's 8 loads stay in flight

#pragma unroll 1
    for (int i = 0; i < 8; ++i) {
        const int c = 2 * i;
        // Phase A: compute buf0 (step c); stage step c+1 -> buf1; load bY
        STAGE_TO(16384, c + 1)
        LOADB(bY, c + 1)
        COMPUTE(smem, bX)
        wait8_barrier();
        // Phase B: compute buf1 (step c+1); stage step c+2 -> buf0; load bX
        if (i < 7) {
            STAGE_TO(0, c + 2)
            LOADB(bX, c + 2)
        }
        COMPUTE(smem + 8192, bY)
        wait8_barrier();
    }
#undef STAGE_TO
#undef LOADB
#undef COMPUTE

    if (MODE == 0) {
        float cB[4], cW[4]; int cCol[4];
#pragma unroll
        for (int tj = 0; tj < 4; ++tj) {
            cCol[tj] = colBase + wc * 64 + tj * 16 + lr;
            cB[tj] = bias[cCol[tj]];
            cW[tj] = W3[cCol[tj]];
        }
#pragma unroll
        for (int ti = 0; ti < 4; ++ti) {
#pragma unroll
            for (int r = 0; r < 4; ++r) {
                int row = rowBase + wr * 64 + ti * 16 + lq * 4 + r;
                float ys = 0.f;
#pragma unroll
                for (int tj = 0; tj < 4; ++tj) {
                    float z2 = tanhf(acc[ti][tj][r] + cB[tj]);
                    ys += z2 * cW[tj];
                    Out[(size_t)row * HS + cCol[tj]] = f2bf((1.f - z2 * z2) * cW[tj]);
                }
                ys += __shfl_xor(ys, 1); ys += __shfl_xor(ys, 2);
                ys += __shfl_xor(ys, 4); ys += __shfl_xor(ys, 8);
                if (lr == 0) atomicAdd(&yOut[row], ys);
            }
        }
    } else {
        // c = U*(1-z1^2) -> LDS [128 rows][stride 136 u16]
#pragma unroll
        for (int ti = 0; ti < 4; ++ti)
#pragma unroll
            for (int r = 0; r < 4; ++r) {
                int rowl = wr * 64 + ti * 16 + lq * 4 + r;
                const size_t zrow = (size_t)(rowBase + rowl) * HS + colBase;
#pragma unroll
                for (int tj = 0; tj < 4; ++tj) {
                    int coll = wc * 64 + tj * 16 + lr;
                    float z1 = bf2f(Z1[zrow + coll]);
                    smem[rowl * 136 + coll] =
                        f2bf(acc[ti][tj][r] * (1.f - z1 * z1));
                }
            }
        __syncthreads();
        // D[32x8 per wave] = c-rows [wave*32,+32) @ W1T-slice, via 8 MFMAs
        f32x4 dd[2] = {};
#pragma unroll
        for (int h = 0; h < 2; ++h)
#pragma unroll
            for (int kb = 0; kb < 4; ++kb) {
                short8 aF = *(const short8*)(smem + (wave * 32 + h * 16 + lr) * 136
                                             + kb * 32 + lq * 8);
                short8 bF = *(const short8*)(W1T + (size_t)lr * HS + colBase
                                             + kb * 32 + lq * 8);
                dd[h] = __builtin_amdgcn_mfma_f32_16x16x32_bf16(aF, bF, dd[h], 0, 0, 0);
            }
        if (lr < 8) {
#pragma unroll
            for (int h = 0; h < 2; ++h) {
                int row = rowBase + wave * 32 + h * 16 + lq * 4;
#pragma unroll
                for (int rg = 0; rg < 4; ++rg)
                    atomicAdd(&dOut[(size_t)lr * NXS + row + rg], dd[h][rg]);
            }
        }
    }
}

extern "C" void kernel_launch(void* const* d_in, const int* in_sizes, int n_in,
                              void* d_out, int out_size, void* d_ws, size_t ws_size,
                              hipStream_t stream) {
    (void)in_sizes; (void)n_in; (void)out_size; (void)ws_size;
    const float* x  = (const float*)d_in[0];
    const float* W1 = (const float*)d_in[1];
    const float* b1 = (const float*)d_in[2];
    const float* W2 = (const float*)d_in[3];
    const float* b2 = (const float*)d_in[4];
    const float* W3 = (const float*)d_in[5];
    const float* b3 = (const float*)d_in[6];
    float* out = (float*)d_out;

    char* ws = (char*)d_ws;
    // ws layout:
    //   [0, 16MB)     Z1 bf16 (live through GEMM2's epilogue)
    //   [16MB, 32MB)  V bf16
    //   [32MB, 34MB)  Bp1 bf16 fragment-packed W2   (GEMM1 B)
    //   [34MB, 36MB)  Bp2 bf16 fragment-packed W2^T (GEMM2 B)
    //   [36MB, +32KB) W1T bf16 [16][1024] (rows 8..15 zero)
    uint16_t* Z1  = (uint16_t*)(ws);
    uint16_t* V   = (uint16_t*)(ws + (size_t)16 * 1024 * 1024);
    uint16_t* Bp1 = (uint16_t*)(ws + (size_t)32 * 1024 * 1024);
    uint16_t* Bp2 = (uint16_t*)(ws + (size_t)34 * 1024 * 1024);
    uint16_t* W1T = (uint16_t*)(ws + (size_t)36 * 1024 * 1024);

    k01<<<2400, 256, 0, stream>>>(x, W1, b1, W2, b3, Z1, Bp1, Bp2, W1T, out);
    gemm_k<0><<<dim3(NXS / 128, HS / 128), 256, 0, stream>>>(
        Z1, Bp1, b2, W3, V, out, nullptr, nullptr, nullptr);
    gemm_k<1><<<dim3(NXS / 128, HS / 128), 256, 0, stream>>>(
        V, Bp2, nullptr, nullptr, nullptr, nullptr, Z1, W1T, out + NXS);
}

// Round 5
// 134.601 us; speedup vs baseline: 1.0483x; 1.0483x over previous
//
#include <hip/hip_runtime.h>
#include <stdint.h>

#define NXS 8192
#define HS  1024

typedef __attribute__((ext_vector_type(8))) short short8;
typedef __attribute__((ext_vector_type(4))) float f32x4;

__device__ __forceinline__ float bf2f(uint32_t b) {
    union { uint32_t u; float f; } c; c.u = b << 16; return c.f;
}
__device__ __forceinline__ uint16_t f2bf(float f) {
    union { float f; uint32_t u; } c; c.f = f;
    return (uint16_t)((c.u + 0x7fffu + ((c.u >> 16) & 1u)) >> 16);
}
__device__ __forceinline__ void async_cp16(const void* g, void* l) {
    __builtin_amdgcn_global_load_lds(
        (const __attribute__((address_space(1))) void*)g,
        (__attribute__((address_space(3))) void*)l,
        16, 0, 0);
}

// ---- K01: merged prep (unchanged) ----
__global__ __launch_bounds__(256) void k01(
    const float* __restrict__ x, const float* __restrict__ W1,
    const float* __restrict__ b1, const float* __restrict__ W2,
    const float* __restrict__ b3, uint16_t* __restrict__ Z1,
    uint16_t* __restrict__ Bp1, uint16_t* __restrict__ Bp2,
    uint16_t* __restrict__ W1T, float* __restrict__ out)
{
    __shared__ float xs[8][8];
    const int b = blockIdx.x, t = threadIdx.x;
    if (b < 1024) {
        const int n0 = b * 8;
        if (t < 64) xs[t >> 3][t & 7] = x[n0 * 8 + t];
        const int j = t * 4;
        float w[4][8];
#pragma unroll
        for (int c = 0; c < 4; ++c) {
            float4 w0 = *(const float4*)(W1 + (j + c) * 8);
            float4 w1 = *(const float4*)(W1 + (j + c) * 8 + 4);
            w[c][0] = w0.x; w[c][1] = w0.y; w[c][2] = w0.z; w[c][3] = w0.w;
            w[c][4] = w1.x; w[c][5] = w1.y; w[c][6] = w1.z; w[c][7] = w1.w;
        }
        float4 bb = *(const float4*)(b1 + j);
        const float bv[4] = {bb.x, bb.y, bb.z, bb.w};
        __syncthreads();
#pragma unroll
        for (int s = 0; s < 8; ++s) {
            ushort4 o;
            uint16_t* op = (uint16_t*)&o;
#pragma unroll
            for (int c = 0; c < 4; ++c) {
                float sum = bv[c];
#pragma unroll
                for (int k = 0; k < 8; ++k) sum += xs[s][k] * w[c][k];
                op[c] = f2bf(tanhf(sum));
            }
            *(ushort4*)(Z1 + (size_t)(n0 + s) * HS + j) = o;
        }
    } else if (b < 1536) {
        const int tid = (b - 1024) * 256 + t;            // 0..131071
        const int l = tid & 63, c = (tid >> 6) & 31, g = tid >> 11;
        const int lr = l & 15, lq = l >> 4;
        const float* src = W2 + (size_t)(g * 16 + lr) * HS + c * 32 + lq * 8;
        float4 a0 = *(const float4*)src;
        float4 a1 = *(const float4*)(src + 4);
        uint16_t o[8];
        o[0] = f2bf(a0.x); o[1] = f2bf(a0.y); o[2] = f2bf(a0.z); o[3] = f2bf(a0.w);
        o[4] = f2bf(a1.x); o[5] = f2bf(a1.y); o[6] = f2bf(a1.z); o[7] = f2bf(a1.w);
        *(ushort4*)(Bp1 + (size_t)tid * 8)     = *(ushort4*)&o[0];
        *(ushort4*)(Bp1 + (size_t)tid * 8 + 4) = *(ushort4*)&o[4];
    } else if (b < 2048) {
        const int tid = (b - 1536) * 256 + t;
        const int l = tid & 63, c = (tid >> 6) & 31, g = tid >> 11;
        const int lr = l & 15, lq = l >> 4;
        uint16_t o[8];
#pragma unroll
        for (int j2 = 0; j2 < 8; ++j2)
            o[j2] = f2bf(W2[(size_t)(c * 32 + lq * 8 + j2) * HS + g * 16 + lr]);
        *(ushort4*)(Bp2 + (size_t)tid * 8)     = *(ushort4*)&o[0];
        *(ushort4*)(Bp2 + (size_t)tid * 8 + 4) = *(ushort4*)&o[4];
    } else if (b < 2336) {
        const int idx = (b - 2048) * 256 + t;            // 0..73727
        out[idx] = (idx < NXS) ? b3[0] : 0.f;
    } else {
        const int idx = (b - 2336) * 256 + t;            // 0..16383
        const int r = idx >> 10, cc = idx & 1023;
        W1T[idx] = (r < 8) ? f2bf(W1[cc * 8 + r]) : (uint16_t)0;
    }
}

// -------- GEMM: 128x128 tile, 4 waves (2x2), BK=64. BOTH operands staged to
// LDS via global_load_lds (m97 structure), double-buffered, plain
// __syncthreads per K-step (compiler manages all waitcnts).
//   A: [128 rows][8 x 16B slots], xor-8 pre-swizzled source -> conflict-free
//      ds_read_b128 at read time.
//   B: [8 groups][2 chunks][64 lanes][16B] per K-step, linear; each wave
//      reads its 4 groups as contiguous 1KB ds_read_b128 (2-way = free).
//      B fetched ONCE per block per phase (was: 2x per phase direct-to-VGPR
//      global loads -> per-phase exposed global latency, the round-0/1/4
//      structural deviation from m97).
// LDS: A dbuf [0,32KB), B dbuf [32KB,64KB). 64KB -> 2 blocks/CU.
// MODE 0: C = Z1 @ W2^T (Bp1); epilogue: tanh -> V (bf16), y atomics
// MODE 1: C = U = V @ W2 (Bp2); fused MFMA dydx epilogue via W1T
template <int MODE>
__global__ __launch_bounds__(256, 2) void gemm_k(
    const uint16_t* __restrict__ A, const uint16_t* __restrict__ Bp,
    const float* __restrict__ bias, const float* __restrict__ W3,
    uint16_t* __restrict__ Out, float* __restrict__ yOut,
    const uint16_t* __restrict__ Z1, const uint16_t* __restrict__ W1T,
    float* __restrict__ dOut)
{
    __shared__ __attribute__((aligned(16))) uint16_t smem[32768];  // 64 KB
    const int t = threadIdx.x;
    const int wave = t >> 6, lane = t & 63;
    const int lq = lane >> 4, lr = lane & 15;
    const int wr = wave >> 1, wc = wave & 1;
    const int rowBase = blockIdx.x * 128;
    const int colBase = blockIdx.y * 128;

    // A staging: 1024 segs of 16B per buffer (128 rows x 8 slots), 4/thread.
    // Source slot pre-swizzled qA = (s&7)^(rA&7); LDS dest linear.
    const uint16_t* gA[4];
#pragma unroll
    for (int i = 0; i < 4; ++i) {
        int s = t + i * 256;
        int rA = s >> 3, qA = (s & 7) ^ (rA & 7);
        gA[i] = A + (size_t)(rowBase + rA) * HS + qA * 8;
    }
    // B staging: 1024 segs of 16B per buffer. seg s: lane16 = s&63,
    // group g' = s>>7 (0..7), chunk-half chl = (s>>6)&1. Per K-step c the
    // global chunk is 2c+chl -> advance by 1024 u16 per step.
    const uint16_t* gB[4];
#pragma unroll
    for (int i = 0; i < 4; ++i) {
        int s = t + i * 256;
        gB[i] = Bp + ((size_t)(colBase >> 4) + (s >> 7)) * 16384
                   + (size_t)((s >> 6) & 1) * 512 + (size_t)(s & 63) * 8;
    }

    f32x4 acc[4][4] = {};

    // prologue: stage K-step 0 (A -> buf0 [0,16K), B -> buf0 [32K,48K))
#pragma unroll
    for (int i = 0; i < 4; ++i)
        async_cp16(gA[i], (char*)smem + t * 16 + i * 4096);
#pragma unroll
    for (int i = 0; i < 4; ++i)
        async_cp16(gB[i], (char*)smem + 32768 + t * 16 + i * 4096);
    __syncthreads();

    int buf = 0;
    for (int c = 0; c < 16; ++c) {
        if (c < 15) {
#pragma unroll
            for (int i = 0; i < 4; ++i)
                async_cp16(gA[i] + (c + 1) * 64,
                           (char*)smem + (buf ^ 1) * 16384 + t * 16 + i * 4096);
#pragma unroll
            for (int i = 0; i < 4; ++i)
                async_cp16(gB[i] + (c + 1) * 1024,
                           (char*)smem + 32768 + (buf ^ 1) * 16384 + t * 16 + i * 4096);
        }
        const uint16_t* pA  = smem + buf * 8192;
        const uint16_t* pBl = smem + 16384 + buf * 8192;
#pragma unroll
        for (int kk = 0; kk < 2; ++kk) {
            short8 bfrag[4];
#pragma unroll
            for (int tj = 0; tj < 4; ++tj)
                bfrag[tj] = *(const short8*)(pBl
                    + (((wc * 4 + tj) * 2 + kk) * 64 + lane) * 8);
            short8 af[4];
#pragma unroll
            for (int ti = 0; ti < 4; ++ti) {
                int ar = wr * 64 + ti * 16 + lr;
                af[ti] = *(const short8*)(pA + ar * 64
                          + ((((kk << 2) + lq) ^ (ar & 7)) << 3));
            }
#pragma unroll
            for (int ti = 0; ti < 4; ++ti)
#pragma unroll
                for (int tj = 0; tj < 4; ++tj)
                    acc[ti][tj] = __builtin_amdgcn_mfma_f32_16x16x32_bf16(
                        af[ti], bfrag[tj], acc[ti][tj], 0, 0, 0);
        }
        __syncthreads();
        buf ^= 1;
    }

    if (MODE == 0) {
        float cB[4], cW[4]; int cCol[4];
#pragma unroll
        for (int tj = 0; tj < 4; ++tj) {
            cCol[tj] = colBase + wc * 64 + tj * 16 + lr;
            cB[tj] = bias[cCol[tj]];
            cW[tj] = W3[cCol[tj]];
        }
#pragma unroll
        for (int ti = 0; ti < 4; ++ti) {
#pragma unroll
            for (int r = 0; r < 4; ++r) {
                int row = rowBase + wr * 64 + ti * 16 + lq * 4 + r;
                float ys = 0.f;
#pragma unroll
                for (int tj = 0; tj < 4; ++tj) {
                    float z2 = tanhf(acc[ti][tj][r] + cB[tj]);
                    ys += z2 * cW[tj];
                    Out[(size_t)row * HS + cCol[tj]] = f2bf((1.f - z2 * z2) * cW[tj]);
                }
                ys += __shfl_xor(ys, 1); ys += __shfl_xor(ys, 2);
                ys += __shfl_xor(ys, 4); ys += __shfl_xor(ys, 8);
                if (lr == 0) atomicAdd(&yOut[row], ys);
            }
        }
    } else {
        // c = U*(1-z1^2) -> LDS [128 rows][stride 136 u16] (reuses smem)
#pragma unroll
        for (int ti = 0; ti < 4; ++ti)
#pragma unroll
            for (int r = 0; r < 4; ++r) {
                int rowl = wr * 64 + ti * 16 + lq * 4 + r;
                const size_t zrow = (size_t)(rowBase + rowl) * HS + colBase;
#pragma unroll
                for (int tj = 0; tj < 4; ++tj) {
                    int coll = wc * 64 + tj * 16 + lr;
                    float z1 = bf2f(Z1[zrow + coll]);
                    smem[rowl * 136 + coll] =
                        f2bf(acc[ti][tj][r] * (1.f - z1 * z1));
                }
            }
        __syncthreads();
        // D[32x8 per wave] = c-rows [wave*32,+32) @ W1T-slice, via 8 MFMAs
        f32x4 dd[2] = {};
#pragma unroll
        for (int h = 0; h < 2; ++h)
#pragma unroll
            for (int kb = 0; kb < 4; ++kb) {
                short8 aF = *(const short8*)(smem + (wave * 32 + h * 16 + lr) * 136
                                             + kb * 32 + lq * 8);
                short8 bF = *(const short8*)(W1T + (size_t)lr * HS + colBase
                                             + kb * 32 + lq * 8);
                dd[h] = __builtin_amdgcn_mfma_f32_16x16x32_bf16(aF, bF, dd[h], 0, 0, 0);
            }
        if (lr < 8) {
#pragma unroll
            for (int h = 0; h < 2; ++h) {
                int row = rowBase + wave * 32 + h * 16 + lq * 4;
#pragma unroll
                for (int rg = 0; rg < 4; ++rg)
                    atomicAdd(&dOut[(size_t)lr * NXS + row + rg], dd[h][rg]);
            }
        }
    }
}

extern "C" void kernel_launch(void* const* d_in, const int* in_sizes, int n_in,
                              void* d_out, int out_size, void* d_ws, size_t ws_size,
                              hipStream_t stream) {
    (void)in_sizes; (void)n_in; (void)out_size; (void)ws_size;
    const float* x  = (const float*)d_in[0];
    const float* W1 = (const float*)d_in[1];
    const float* b1 = (const float*)d_in[2];
    const float* W2 = (const float*)d_in[3];
    const float* b2 = (const float*)d_in[4];
    const float* W3 = (const float*)d_in[5];
    const float* b3 = (const float*)d_in[6];
    float* out = (float*)d_out;

    char* ws = (char*)d_ws;
    // ws layout:
    //   [0, 16MB)     Z1 bf16 (live through GEMM2's epilogue)
    //   [16MB, 32MB)  V bf16
    //   [32MB, 34MB)  Bp1 bf16 fragment-packed W2   (GEMM1 B)
    //   [34MB, 36MB)  Bp2 bf16 fragment-packed W2^T (GEMM2 B)
    //   [36MB, +32KB) W1T bf16 [16][1024] (rows 8..15 zero)
    uint16_t* Z1  = (uint16_t*)(ws);
    uint16_t* V   = (uint16_t*)(ws + (size_t)16 * 1024 * 1024);
    uint16_t* Bp1 = (uint16_t*)(ws + (size_t)32 * 1024 * 1024);
    uint16_t* Bp2 = (uint16_t*)(ws + (size_t)34 * 1024 * 1024);
    uint16_t* W1T = (uint16_t*)(ws + (size_t)36 * 1024 * 1024);

    k01<<<2400, 256, 0, stream>>>(x, W1, b1, W2, b3, Z1, Bp1, Bp2, W1T, out);
    gemm_k<0><<<dim3(NXS / 128, HS / 128), 256, 0, stream>>>(
        Z1, Bp1, b2, W3, V, out, nullptr, nullptr, nullptr);
    gemm_k<1><<<dim3(NXS / 128, HS / 128), 256, 0, stream>>>(
        V, Bp2, nullptr, nullptr, nullptr, nullptr, Z1, W1T, out + NXS);
}

// Round 6
// 132.217 us; speedup vs baseline: 1.0672x; 1.0180x over previous
//
#include <hip/hip_runtime.h>
#include <stdint.h>

#define NXS 8192
#define HS  1024

typedef __attribute__((ext_vector_type(8))) short short8;
typedef __attribute__((ext_vector_type(4))) float f32x4;

__device__ __forceinline__ float bf2f(uint32_t b) {
    union { uint32_t u; float f; } c; c.u = b << 16; return c.f;
}
__device__ __forceinline__ uint16_t f2bf(float f) {
    union { float f; uint32_t u; } c; c.f = f;
    return (uint16_t)((c.u + 0x7fffu + ((c.u >> 16) & 1u)) >> 16);
}
// fast tanh: 1 - 2/(e^{2x}+1). v_exp_f32 + v_rcp_f32 via HIP fast intrinsics
// (compiler-managed hazards). |err| ~1e-5 << bf16 quantum. Clamp +-15 so
// e^{2x} never overflows.
__device__ __forceinline__ float fast_tanh(float x) {
    float xc = fminf(fmaxf(x, -15.f), 15.f);
    return 1.f - __fdividef(2.f, __expf(2.f * xc) + 1.f);
}
__device__ __forceinline__ void async_cp16(const void* g, void* l) {
    __builtin_amdgcn_global_load_lds(
        (const __attribute__((address_space(1))) void*)g,
        (__attribute__((address_space(3))) void*)l,
        16, 0, 0);
}

// ---- K01: merged prep (fast_tanh swapped in; otherwise unchanged) ----
__global__ __launch_bounds__(256) void k01(
    const float* __restrict__ x, const float* __restrict__ W1,
    const float* __restrict__ b1, const float* __restrict__ W2,
    const float* __restrict__ b3, uint16_t* __restrict__ Z1,
    uint16_t* __restrict__ Bp1, uint16_t* __restrict__ Bp2,
    uint16_t* __restrict__ W1T, float* __restrict__ out)
{
    __shared__ float xs[8][8];
    const int b = blockIdx.x, t = threadIdx.x;
    if (b < 1024) {
        const int n0 = b * 8;
        if (t < 64) xs[t >> 3][t & 7] = x[n0 * 8 + t];
        const int j = t * 4;
        float w[4][8];
#pragma unroll
        for (int c = 0; c < 4; ++c) {
            float4 w0 = *(const float4*)(W1 + (j + c) * 8);
            float4 w1 = *(const float4*)(W1 + (j + c) * 8 + 4);
            w[c][0] = w0.x; w[c][1] = w0.y; w[c][2] = w0.z; w[c][3] = w0.w;
            w[c][4] = w1.x; w[c][5] = w1.y; w[c][6] = w1.z; w[c][7] = w1.w;
        }
        float4 bb = *(const float4*)(b1 + j);
        const float bv[4] = {bb.x, bb.y, bb.z, bb.w};
        __syncthreads();
#pragma unroll
        for (int s = 0; s < 8; ++s) {
            ushort4 o;
            uint16_t* op = (uint16_t*)&o;
#pragma unroll
            for (int c = 0; c < 4; ++c) {
                float sum = bv[c];
#pragma unroll
                for (int k = 0; k < 8; ++k) sum += xs[s][k] * w[c][k];
                op[c] = f2bf(fast_tanh(sum));
            }
            *(ushort4*)(Z1 + (size_t)(n0 + s) * HS + j) = o;
        }
    } else if (b < 1536) {
        const int tid = (b - 1024) * 256 + t;            // 0..131071
        const int l = tid & 63, c = (tid >> 6) & 31, g = tid >> 11;
        const int lr = l & 15, lq = l >> 4;
        const float* src = W2 + (size_t)(g * 16 + lr) * HS + c * 32 + lq * 8;
        float4 a0 = *(const float4*)src;
        float4 a1 = *(const float4*)(src + 4);
        uint16_t o[8];
        o[0] = f2bf(a0.x); o[1] = f2bf(a0.y); o[2] = f2bf(a0.z); o[3] = f2bf(a0.w);
        o[4] = f2bf(a1.x); o[5] = f2bf(a1.y); o[6] = f2bf(a1.z); o[7] = f2bf(a1.w);
        *(ushort4*)(Bp1 + (size_t)tid * 8)     = *(ushort4*)&o[0];
        *(ushort4*)(Bp1 + (size_t)tid * 8 + 4) = *(ushort4*)&o[4];
    } else if (b < 2048) {
        const int tid = (b - 1536) * 256 + t;
        const int l = tid & 63, c = (tid >> 6) & 31, g = tid >> 11;
        const int lr = l & 15, lq = l >> 4;
        uint16_t o[8];
#pragma unroll
        for (int j2 = 0; j2 < 8; ++j2)
            o[j2] = f2bf(W2[(size_t)(c * 32 + lq * 8 + j2) * HS + g * 16 + lr]);
        *(ushort4*)(Bp2 + (size_t)tid * 8)     = *(ushort4*)&o[0];
        *(ushort4*)(Bp2 + (size_t)tid * 8 + 4) = *(ushort4*)&o[4];
    } else if (b < 2336) {
        const int idx = (b - 2048) * 256 + t;            // 0..73727
        out[idx] = (idx < NXS) ? b3[0] : 0.f;
    } else {
        const int idx = (b - 2336) * 256 + t;            // 0..16383
        const int r = idx >> 10, cc = idx & 1023;
        W1T[idx] = (r < 8) ? f2bf(W1[cc * 8 + r]) : (uint16_t)0;
    }
}

// -------- GEMM: 128x128 tile, 4 waves (2x2), BK=32, TRIPLE-buffered LDS,
// counted-vmcnt schedule (T4, m218 mechanism). ALL global traffic in the
// K-loop goes through global_load_lds -> the compiler has NO VGPR-consumed
// vmem loads to auto-drain; the only vmcnt waits are ours.
//   Per step c: issue stage(c+2) [4 gload_lds] -> ds_read+MFMA on buf[c%3]
//   -> asm vmcnt(4) (retire stage(c+1), leave stage(c+2) in flight) ->
//   raw s_barrier. Each stage has ~2 compute phases to cover L2/L3 latency.
//   Steps 30/31 peel to vmcnt(0). Hazards: stage(c+2) overwrites
//   buf[(c-1)%3], whose ds_reads all retired before the c-1 -> c barrier
//   (each feeds an MFMA before it); WAW retired one step earlier.
// LDS: 3 bufs x (A 8K + B 8K) = 48 KB -> 2 blocks/CU.
// A swizzle (BK=32, 4 slots/row): slot = lq ^ ((row>>1)&3) -> 2-way = free.
// MODE 0: C = Z1 @ W2^T (Bp1); epilogue: tanh -> V (bf16), y atomics
// MODE 1: C = U = V @ W2 (Bp2); fused MFMA dydx epilogue via W1T
template <int MODE>
__global__ __launch_bounds__(256, 2) void gemm_k(
    const uint16_t* __restrict__ A, const uint16_t* __restrict__ Bp,
    const float* __restrict__ bias, const float* __restrict__ W3,
    uint16_t* __restrict__ Out, float* __restrict__ yOut,
    const uint16_t* __restrict__ Z1, const uint16_t* __restrict__ W1T,
    float* __restrict__ dOut)
{
    // 3 x 16 KB K-loop buffers; MODE1 epilogue c-matrix 128x136 u16 fits.
    __shared__ __attribute__((aligned(16))) uint16_t smem[24576];  // 48 KB
    const int t = threadIdx.x;
    const int wave = t >> 6, lane = t & 63;
    const int lq = lane >> 4, lr = lane & 15;
    const int wr = wave >> 1, wc = wave & 1;
    const int rowBase = blockIdx.x * 128;
    const int colBase = blockIdx.y * 128;

    // A staging: 512 segs of 16B per step (128 rows x 4 slots), 2/thread.
    // Source slot pre-swizzled qA = sl ^ ((rA>>1)&3); LDS dest linear.
    // B staging: 512 segs (8 groups x 64 lanes), 2/thread, linear.
    const uint16_t* gA0;
    const uint16_t* gA1;
    {
        int s0 = t,       r0 = s0 >> 2, q0 = (s0 & 3) ^ ((r0 >> 1) & 3);
        int s1 = t + 256, r1 = s1 >> 2, q1 = (s1 & 3) ^ ((r1 >> 1) & 3);
        gA0 = A + (size_t)(rowBase + r0) * HS + q0 * 8;
        gA1 = A + (size_t)(rowBase + r1) * HS + q1 * 8;
    }
    const uint16_t* gB0;
    const uint16_t* gB1;
    {
        int s0 = t,       s1 = t + 256;
        gB0 = Bp + ((size_t)(colBase >> 4) + (s0 >> 6)) * 16384 + (size_t)(s0 & 63) * 8;
        gB1 = Bp + ((size_t)(colBase >> 4) + (s1 >> 6)) * 16384 + (size_t)(s1 & 63) * 8;
    }
    const int ldsA0 = t * 16;                 // bytes within buffer
    const int ldsA1 = t * 16 + 4096;
    const int ldsB0 = t * 16 + 8192;
    const int ldsB1 = t * 16 + 12288;

    f32x4 acc[4][4] = {};

    // prologue: stage step 0 -> buf0, step 1 -> buf1 (8 outstanding)
    async_cp16(gA0,       (char*)smem + ldsA0);
    async_cp16(gA1,       (char*)smem + ldsA1);
    async_cp16(gB0,       (char*)smem + ldsB0);
    async_cp16(gB1,       (char*)smem + ldsB1);
    async_cp16(gA0 + 32,  (char*)smem + 16384 + ldsA0);
    async_cp16(gA1 + 32,  (char*)smem + 16384 + ldsA1);
    async_cp16(gB0 + 512, (char*)smem + 16384 + ldsB0);
    async_cp16(gB1 + 512, (char*)smem + 16384 + ldsB1);
    // advance source pointers to step-2 positions
    gA0 += 64; gA1 += 64; gB0 += 1024; gB1 += 1024;
    // retire stage(0) only; stage(1) stays in flight
    asm volatile("s_waitcnt vmcnt(4)" ::: "memory");
    __builtin_amdgcn_s_barrier();

    int rb = 0;   // read buffer byte base / 16384 for step c
    int wb = 2;   // write buffer for stage(c+2)
#pragma unroll 1
    for (int c = 0; c < 32; ++c) {
        if (c < 30) {
            char* d = (char*)smem + wb * 16384;
            async_cp16(gA0, d + ldsA0);
            async_cp16(gA1, d + ldsA1);
            async_cp16(gB0, d + ldsB0);
            async_cp16(gB1, d + ldsB1);
            gA0 += 32; gA1 += 32; gB0 += 512; gB1 += 512;
            asm volatile("" ::: "memory");   // keep stage issue ahead of reads
        }
        const uint16_t* pA  = smem + rb * 8192;
        const uint16_t* pBl = pA + 4096;
        short8 bfrag[4];
#pragma unroll
        for (int tj = 0; tj < 4; ++tj)
            bfrag[tj] = *(const short8*)(pBl + (((wc << 2) + tj) * 64 + lane) * 8);
        short8 af[4];
#pragma unroll
        for (int ti = 0; ti < 4; ++ti) {
            int ar = wr * 64 + ti * 16 + lr;
            af[ti] = *(const short8*)(pA + ar * 32
                      + ((lq ^ ((ar >> 1) & 3)) << 3));
        }
#pragma unroll
        for (int ti = 0; ti < 4; ++ti)
#pragma unroll
            for (int tj = 0; tj < 4; ++tj)
                acc[ti][tj] = __builtin_amdgcn_mfma_f32_16x16x32_bf16(
                    af[ti], bfrag[tj], acc[ti][tj], 0, 0, 0);
        if (c < 30) {
            // outstanding: stage(c+1) 4 + stage(c+2) 4 -> retire stage(c+1)
            asm volatile("s_waitcnt vmcnt(4)" ::: "memory");
        } else {
            // c=30: only stage(31) outstanding; c=31: none
            asm volatile("s_waitcnt vmcnt(0)" ::: "memory");
        }
        __builtin_amdgcn_s_barrier();
        rb = (rb == 2) ? 0 : rb + 1;
        wb = (wb == 2) ? 0 : wb + 1;
    }

    if (MODE == 0) {
        float cB[4], cW[4]; int cCol[4];
#pragma unroll
        for (int tj = 0; tj < 4; ++tj) {
            cCol[tj] = colBase + wc * 64 + tj * 16 + lr;
            cB[tj] = bias[cCol[tj]];
            cW[tj] = W3[cCol[tj]];
        }
#pragma unroll
        for (int ti = 0; ti < 4; ++ti) {
#pragma unroll
            for (int r = 0; r < 4; ++r) {
                int row = rowBase + wr * 64 + ti * 16 + lq * 4 + r;
                float ys = 0.f;
#pragma unroll
                for (int tj = 0; tj < 4; ++tj) {
                    float z2 = fast_tanh(acc[ti][tj][r] + cB[tj]);
                    ys += z2 * cW[tj];
                    Out[(size_t)row * HS + cCol[tj]] = f2bf((1.f - z2 * z2) * cW[tj]);
                }
                ys += __shfl_xor(ys, 1); ys += __shfl_xor(ys, 2);
                ys += __shfl_xor(ys, 4); ys += __shfl_xor(ys, 8);
                if (lr == 0) atomicAdd(&yOut[row], ys);
            }
        }
    } else {
        // c = U*(1-z1^2) -> LDS [128 rows][stride 136 u16] (reuses smem)
#pragma unroll
        for (int ti = 0; ti < 4; ++ti)
#pragma unroll
            for (int r = 0; r < 4; ++r) {
                int rowl = wr * 64 + ti * 16 + lq * 4 + r;
                const size_t zrow = (size_t)(rowBase + rowl) * HS + colBase;
#pragma unroll
                for (int tj = 0; tj < 4; ++tj) {
                    int coll = wc * 64 + tj * 16 + lr;
                    float z1 = bf2f(Z1[zrow + coll]);
                    smem[rowl * 136 + coll] =
                        f2bf(acc[ti][tj][r] * (1.f - z1 * z1));
                }
            }
        __syncthreads();
        // D[32x8 per wave] = c-rows [wave*32,+32) @ W1T-slice, via 8 MFMAs
        f32x4 dd[2] = {};
#pragma unroll
        for (int h = 0; h < 2; ++h)
#pragma unroll
            for (int kb = 0; kb < 4; ++kb) {
                short8 aF = *(const short8*)(smem + (wave * 32 + h * 16 + lr) * 136
                                             + kb * 32 + lq * 8);
                short8 bF = *(const short8*)(W1T + (size_t)lr * HS + colBase
                                             + kb * 32 + lq * 8);
                dd[h] = __builtin_amdgcn_mfma_f32_16x16x32_bf16(aF, bF, dd[h], 0, 0, 0);
            }
        if (lr < 8) {
#pragma unroll
            for (int h = 0; h < 2; ++h) {
                int row = rowBase + wave * 32 + h * 16 + lq * 4;
#pragma unroll
                for (int rg = 0; rg < 4; ++rg)
                    atomicAdd(&dOut[(size_t)lr * NXS + row + rg], dd[h][rg]);
            }
        }
    }
}

extern "C" void kernel_launch(void* const* d_in, const int* in_sizes, int n_in,
                              void* d_out, int out_size, void* d_ws, size_t ws_size,
                              hipStream_t stream) {
    (void)in_sizes; (void)n_in; (void)out_size; (void)ws_size;
    const float* x  = (const float*)d_in[0];
    const float* W1 = (const float*)d_in[1];
    const float* b1 = (const float*)d_in[2];
    const float* W2 = (const float*)d_in[3];
    const float* b2 = (const float*)d_in[4];
    const float* W3 = (const float*)d_in[5];
    const float* b3 = (const float*)d_in[6];
    float* out = (float*)d_out;

    char* ws = (char*)d_ws;
    // ws layout:
    //   [0, 16MB)     Z1 bf16 (live through GEMM2's epilogue)
    //   [16MB, 32MB)  V bf16
    //   [32MB, 34MB)  Bp1 bf16 fragment-packed W2   (GEMM1 B)
    //   [34MB, 36MB)  Bp2 bf16 fragment-packed W2^T (GEMM2 B)
    //   [36MB, +32KB) W1T bf16 [16][1024] (rows 8..15 zero)
    uint16_t* Z1  = (uint16_t*)(ws);
    uint16_t* V   = (uint16_t*)(ws + (size_t)16 * 1024 * 1024);
    uint16_t* Bp1 = (uint16_t*)(ws + (size_t)32 * 1024 * 1024);
    uint16_t* Bp2 = (uint16_t*)(ws + (size_t)34 * 1024 * 1024);
    uint16_t* W1T = (uint16_t*)(ws + (size_t)36 * 1024 * 1024);

    k01<<<2400, 256, 0, stream>>>(x, W1, b1, W2, b3, Z1, Bp1, Bp2, W1T, out);
    gemm_k<0><<<dim3(NXS / 128, HS / 128), 256, 0, stream>>>(
        Z1, Bp1, b2, W3, V, out, nullptr, nullptr, nullptr);
    gemm_k<1><<<dim3(NXS / 128, HS / 128), 256, 0, stream>>>(
        V, Bp2, nullptr, nullptr, nullptr, nullptr, Z1, W1T, out + NXS);
}